// Round 13
// baseline (131.410 us; speedup 1.0000x reference)
//
#include <hip/hip_runtime.h>

// SimpleDiagonalRNN: h_t = a*h_{t-1} + x_t, a = 1 - relu(w), x [8,4096,512] f32.
//
// Correctness model (stable since r0):
//  * a = 1 - relu(w) <= 1 always; ~2% of channels have a < -1 -> reference
//    diverges to +/-inf; pass criterion tolerates any FINITE value there
//    (failure mode is NaN from same-sign inf - inf). Output must be finite.
//  * Clamp at +/-1e15 on EVERY product/FMA: |a|<~5, all states <=1e15 ->
//    every intermediate <= ~2e30 << FLT_MAX. No inf formed -> no NaN.
//  * For contracting channels (|a|<=1) the clamp never fires -> all parallel
//    re-associations are exact mod FP rounding (r4/r8/r11/r12 all passed).
//
// Perf history / model:
//  * dur_us ~= 66-72us harness overhead (poison fills) + kernel total.
//  * r3/r7 two-dispatch: ~52us kernels. r8 in-block serial chunks: 52us.
//  * r11 3-phase w/ hl[16] regs: VGPR=60 (needs 64+) -> chunk spilled to
//    scratch. WRITE 88.8MB (67 out + ~22 scratch), VALUBusy 6.4%, 53us.
//  * r12 same + __launch_bounds__(1024,4): VGPR STILL 60, STILL spilled,
//    52us. Allocator pins ~60 VGPR (≈512/8 budget) regardless of bounds.
//    CONCLUSION: register residency across barriers is unavailable; stop
//    fighting the allocator.
//  * r13 (this): fused TWO-PASS, no cross-phase register state:
//      P1: aggregate-only chunk scan, PF=4 two-batch pipeline in NAMED
//          registers (peak ~52 VGPR by design -> no spill possible).
//      P2: unchanged (verified r11/r12): Kogge-Stone over 256 aggregates.
//      P3: REPLAY chunk from x (L2/L3-hot; r1/r12 FETCH=33MB prove x
//          re-reads mostly hit cache), seeded with LDS carry-in; NT stores.
//    = r3's proven structure with the dispatch drain -> 1 barrier, global
//    Lc -> LDS, serial prefix -> parallel P2. x HBM-read once, out once.

#define RB 8
#define RT 4096
#define RD 512
#define DG (RD / 4)      // 128 float4 groups over d
#define CL 16            // timesteps per chunk
#define NC (RT / CL)     // 256 chunks per block
#define TPB 1024         // 16 waves = 4 waves/EU
#define HB 1e15f

typedef float f32x4 __attribute__((ext_vector_type(4)));

__device__ __forceinline__ float sclamp(float v) {
    return fminf(fmaxf(v, -HB), HB);
}
__device__ __forceinline__ f32x4 sclamp4(f32x4 v) {
    v.x = sclamp(v.x); v.y = sclamp(v.y);
    v.z = sclamp(v.z); v.w = sclamp(v.w);
    return v;
}
__device__ __forceinline__ f32x4 ld4(const float4* __restrict__ p) {
    return *(const f32x4* __restrict__)p;
}
__device__ __forceinline__ f32x4 shfl4(f32x4 v, int src) {
    f32x4 r;
    r.x = __shfl(v.x, src, 64);
    r.y = __shfl(v.y, src, 64);
    r.z = __shfl(v.z, src, 64);
    r.w = __shfl(v.w, src, 64);
    return r;
}
__device__ __forceinline__ f32x4 relu_decay(float4 wq) {
    f32x4 a;
    a.x = 1.0f - fmaxf(wq.x, 0.0f);
    a.y = 1.0f - fmaxf(wq.y, 0.0f);
    a.z = 1.0f - fmaxf(wq.z, 0.0f);
    a.w = 1.0f - fmaxf(wq.w, 0.0f);
    return a;
}

// One block per (b, 16-channel tile): grid 256, 1024 threads (16 waves).
// Thread map (P1/P3): g = tid&3 (float4 within tile), c = tid>>2 (chunk).
__global__ void __launch_bounds__(TPB, 4)
rnn_fused2(const float4* __restrict__ x4, const float4* __restrict__ w4,
           float4* __restrict__ out4) {
    const int tid = threadIdx.x;
    const int g   = tid & 3;
    const int c   = tid >> 2;            // 0..255

    // XCD-pairing swizzle (verified r8..r12, correctness-neutral):
    // tiles 2p,2p+1 (sharing 128B lines) land on blocks with equal bid%8.
    const int bid  = blockIdx.x;
    const int u    = bid & 7;
    const int half = (bid >> 3) & 1;
    const int rest = bid >> 4;           // 0..15
    const int pair = rest * 8 + u;       // 0..127
    const int b    = pair >> 4;          // 0..7
    const int tile = 2 * (pair & 15) + half;  // 0..31

    const f32x4 A1 = relu_decay(w4[tile * 4 + g]);

    // LDS, padded *5 (16B elems) to break stride-bank alignment.
    __shared__ f32x4 Wagg[NC * 5];       // chunk aggregates   [c*5+g]
    __shared__ f32x4 CI[NC * 5];         // chunk carry-ins    [c*5+g]
    __shared__ f32x4 WinAgg[4 * 5];      // window aggregates  [q*5+g]

    const size_t base = ((size_t)b * RT + (size_t)c * CL) * DG
                      + (size_t)(tile * 4 + g);
    const float4* __restrict__ xb = x4 + base;

    // ---- Phase 1: aggregate-only scan, PF=4 two-batch pipeline ----
    // Named registers only; peak live set ~52 VGPR -> no spill possible.
    {
        f32x4 h = {0.f, 0.f, 0.f, 0.f};
        f32x4 v0 = ld4(xb + 0 * DG), v1 = ld4(xb + 1 * DG);
        f32x4 v2 = ld4(xb + 2 * DG), v3 = ld4(xb + 3 * DG);
#define CONSUME4()                                   \
        h = sclamp4(A1 * h + v0);                    \
        h = sclamp4(A1 * h + v1);                    \
        h = sclamp4(A1 * h + v2);                    \
        h = sclamp4(A1 * h + v3);
#define PREFETCH4(B)                                 \
        { f32x4 n0 = ld4(xb + (size_t)((B) + 0) * DG);   \
          f32x4 n1 = ld4(xb + (size_t)((B) + 1) * DG);   \
          f32x4 n2 = ld4(xb + (size_t)((B) + 2) * DG);   \
          f32x4 n3 = ld4(xb + (size_t)((B) + 3) * DG);   \
          CONSUME4();                                \
          v0 = n0; v1 = n1; v2 = n2; v3 = n3; }
        PREFETCH4(4)
        PREFETCH4(8)
        PREFETCH4(12)
        CONSUME4()
#undef PREFETCH4
#undef CONSUME4
        Wagg[c * 5 + g] = h;             // chunk-local end state
    }
    __syncthreads();

    // ---- Phase 2: scan over 256 chunk aggregates (verified r11/r12) ----
    {
        const int w  = tid >> 6;         // wave 0..15
        const int l  = tid & 63;
        const int g2 = w & 3;
        const int q  = w >> 2;           // window 0..3 (64 chunks each)
        const int cc = q * 64 + l;       // this lane's chunk

        // B16 = a^16 for group g2 (recomputed; w4 is L1-hot).
        f32x4 B = relu_decay(w4[tile * 4 + g2]);
#pragma unroll
        for (int i = 0; i < 4; ++i) B = sclamp4(B * B);   // B = a^16

        f32x4 S = Wagg[cc * 5 + g2];
        // Kogge-Stone inclusive over 64 lanes; multiplier B^s lane-uniform.
        f32x4 M = B;
#pragma unroll
        for (int s = 1; s < 64; s <<= 1) {
            f32x4 t = shfl4(S, l >= s ? l - s : l);
            S = (l >= s) ? sclamp4(M * t + S) : S;
            M = sclamp4(M * M);
        }
        // After loop M = B^64 = a^1024 (window aggregate multiplier).
        if (l == 63) WinAgg[q * 5 + g2] = S;
        __syncthreads();

        // Cross-window carry WC = state entering window q.
        f32x4 WC = {0.f, 0.f, 0.f, 0.f};
#pragma unroll
        for (int j = 0; j < 3; ++j) {
            if (j < q) WC = sclamp4(M * WC + WinAgg[j * 5 + g2]);
        }
        // Full inclusive state S_cc = S + B^(l+1) * WC.
        const int n = l + 1;             // 1..64
        f32x4 P = {1.f, 1.f, 1.f, 1.f};
        f32x4 mm = B;
#pragma unroll
        for (int k = 0; k < 7; ++k) {
            if ((n >> k) & 1) P = sclamp4(P * mm);
            mm = sclamp4(mm * mm);
        }
        f32x4 Sf = sclamp4(S + P * WC);
        // Carry-in for chunk cc+1 is S_cc; chunk 0 gets 0.
        if (cc < NC - 1) CI[(cc + 1) * 5 + g2] = Sf;
        if (cc == 0)     CI[0 * 5 + g2] = (f32x4){0.f, 0.f, 0.f, 0.f};
    }
    __syncthreads();

    // ---- Phase 3: replay chunk from (L2/L3-hot) x with true carry-in ----
    {
        float4* __restrict__ ob = out4 + base;
        f32x4 h = CI[c * 5 + g];         // state entering this chunk
        f32x4 v0 = ld4(xb + 0 * DG), v1 = ld4(xb + 1 * DG);
        f32x4 v2 = ld4(xb + 2 * DG), v3 = ld4(xb + 3 * DG);
#define CONSUME4S(B)                                                     \
        h = sclamp4(A1 * h + v0);                                        \
        __builtin_nontemporal_store(h, (f32x4*)(ob + (size_t)((B)+0)*DG)); \
        h = sclamp4(A1 * h + v1);                                        \
        __builtin_nontemporal_store(h, (f32x4*)(ob + (size_t)((B)+1)*DG)); \
        h = sclamp4(A1 * h + v2);                                        \
        __builtin_nontemporal_store(h, (f32x4*)(ob + (size_t)((B)+2)*DG)); \
        h = sclamp4(A1 * h + v3);                                        \
        __builtin_nontemporal_store(h, (f32x4*)(ob + (size_t)((B)+3)*DG));
#define PREFETCH4S(B)                                \
        { f32x4 n0 = ld4(xb + (size_t)((B) + 4) * DG);   \
          f32x4 n1 = ld4(xb + (size_t)((B) + 5) * DG);   \
          f32x4 n2 = ld4(xb + (size_t)((B) + 6) * DG);   \
          f32x4 n3 = ld4(xb + (size_t)((B) + 7) * DG);   \
          CONSUME4S(B);                              \
          v0 = n0; v1 = n1; v2 = n2; v3 = n3; }
        PREFETCH4S(0)
        PREFETCH4S(4)
        PREFETCH4S(8)
        CONSUME4S(12)
#undef PREFETCH4S
#undef CONSUME4S
    }
}

extern "C" void kernel_launch(void* const* d_in, const int* in_sizes, int n_in,
                              void* d_out, int out_size, void* d_ws, size_t ws_size,
                              hipStream_t stream) {
    const float4* x4 = (const float4*)d_in[0];
    const float4* w4 = (const float4*)d_in[1];
    float4* o4 = (float4*)d_out;
    rnn_fused2<<<dim3(RB * (RD / 16)), dim3(TPB), 0, stream>>>(x4, w4, o4);
}